// Round 1
// baseline (20977.998 us; speedup 1.0000x reference)
//
#include <hip/hip_runtime.h>
#include <hip/hip_cooperative_groups.h>

namespace cg = cooperative_groups;

// LSTM: T=512, B=128, I=256, H=1024.
// Persistent cooperative kernel: 256 blocks (1/CU), all 512 timesteps inside,
// grid.sync() between steps.
//  - W bf16 slice resident in LDS for the whole kernel (82 KB/block).
//  - A (x|h) MFMA fragments loaded directly from global (no LDS staging, no
//    per-ktile barriers; compiler pipelines the fully unrolled k-loop).
//  - c state in 2 registers/thread; h ping-pongs in ws as bf16.
// Tiling identical to proven per-step kernel: 2 row-groups x 128 col-groups,
// 64 rows x 32 gate-cols per block, 16x16x32 bf16 MFMA.

#define T_STEPS 512
#define BATCH   128
#define IN_DIM  256
#define HID     1024
#define GATES   4096   // 4*HID
#define KDIM    1280   // IN_DIM + HID

typedef __bf16          bf16x8 __attribute__((ext_vector_type(8)));
typedef unsigned short  u16x8  __attribute__((ext_vector_type(8)));
typedef float           f32x4  __attribute__((ext_vector_type(4)));

__device__ __forceinline__ unsigned short f2bf(float f) {
  unsigned int u = __builtin_bit_cast(unsigned int, f);
  unsigned int r = (u + 0x7FFFu + ((u >> 16) & 1u)) >> 16;  // RNE
  return (unsigned short)r;
}

// W_ih [4096x256] + W_hh [4096x1024] f32 -> fused W_bf [4096][1280] bf16
__global__ void cast_weights(const float* __restrict__ Wih,
                             const float* __restrict__ Whh,
                             unsigned short* __restrict__ Wbf) {
  int gid = blockIdx.x * blockDim.x + threadIdx.x;
  if (gid >= GATES * (KDIM / 4)) return;
  int n  = gid / (KDIM / 4);
  int k4 = (gid % (KDIM / 4)) * 4;
  float4 v;
  if (k4 < IN_DIM) v = *reinterpret_cast<const float4*>(Wih + (size_t)n * IN_DIM + k4);
  else             v = *reinterpret_cast<const float4*>(Whh + (size_t)n * HID + (k4 - IN_DIM));
  ushort4 o;
  o.x = f2bf(v.x); o.y = f2bf(v.y); o.z = f2bf(v.z); o.w = f2bf(v.w);
  *reinterpret_cast<ushort4*>(Wbf + (size_t)n * KDIM + k4) = o;
}

__global__ void init_state(const float* __restrict__ h0,
                           const float* __restrict__ bih,
                           const float* __restrict__ bhh,
                           unsigned short* __restrict__ hbf0,
                           float* __restrict__ bsum) {
  int i = blockIdx.x * blockDim.x + threadIdx.x;
  if (i < BATCH * HID) hbf0[i] = f2bf(h0[i]);
  if (i < GATES) bsum[i] = bih[i] + bhh[i];
}

__global__ __launch_bounds__(256) void lstm_persistent(
    const float* __restrict__ x,              // [T][B][I] f32
    const unsigned short* __restrict__ Wbf,   // [GATES][KDIM] bf16
    const float* __restrict__ bsum,           // [GATES]
    const float* __restrict__ c0,             // [B][H] f32
    unsigned short* __restrict__ hbf,         // 2 x [B][H] bf16 ping-pong
    float* __restrict__ out)                  // [T][B][H] + h_final + c_final
{
  // Bs row stride 1288 shorts = 644 words; 644 % 32 = 4 -> rows shift 4 banks,
  // 16 rows/ds_read_b128 alias 2-way (free). Resident for all timesteps.
  __shared__ __align__(16) unsigned short Bs[32][1288];   // 82,432 B
  __shared__ __align__(16) float Gs[64][36];              //  9,216 B

  const int tid  = threadIdx.x;
  const int bid  = blockIdx.x;
  const int cg_  = bid & 127;           // column group: 8 hidden j's
  const int rg   = bid >> 7;            // row group: 64 batch rows
  const int row0 = rg * 64;
  const int j0   = cg_ * 8;

  const int wave  = tid >> 6;
  const int lane  = tid & 63;
  const int col   = lane & 15;
  const int quad  = lane >> 4;
  const int quad8 = quad * 8;
  const int mrow  = wave * 16 + col;    // this lane's A row within tile
  const int arow  = row0 + mrow;        // global batch row for A fragments

  // ---- load resident B tile: [32 gate-cols][1280 k]
  {
    const int wrow = tid >> 3;          // 0..31 tile gate-col
    const int kcB  = tid & 7;           // 0..7  16B chunk within 64k
    const int gB = wrow >> 3, jjB = wrow & 7;
    const unsigned short* wsrc =
        Wbf + (size_t)(gB * HID + j0 + jjB) * KDIM + kcB * 8;
    #pragma unroll
    for (int kt = 0; kt < KDIM / 64; ++kt)
      *reinterpret_cast<uint4*>(&Bs[wrow][kt * 64 + kcB * 8]) =
          *reinterpret_cast<const uint4*>(wsrc + kt * 64);
  }

  // ---- epilogue ownership (step-invariant): this thread owns cells
  //      (row0+er, j0+jj) and (row0+er+32, j0+jj)
  const int er = tid >> 3;              // 0..31
  const int jj = tid & 7;
  const int j  = j0 + jj;
  const size_t offA = (size_t)(row0 + er) * HID + j;
  const size_t offB = (size_t)(row0 + er + 32) * HID + j;
  float cA = c0[offA], cB = c0[offB];
  float hA = 0.f, hB = 0.f;
  const float bi  = bsum[j];
  const float bf_ = bsum[HID + j];
  const float bg  = bsum[2 * HID + j];
  const float bo  = bsum[3 * HID + j];

  const unsigned short* Bp0 = &Bs[col][quad8];
  const unsigned short* Bp1 = &Bs[16 + col][quad8];

  __syncthreads();
  cg::grid_group grid = cg::this_grid();

  for (int t = 0; t < T_STEPS; ++t) {
    const unsigned short* hin  = hbf + (size_t)(t & 1) * BATCH * HID;
    unsigned short*       hout = hbf + (size_t)((t + 1) & 1) * BATCH * HID;
    const float* xp = x + ((size_t)t * BATCH + arow) * IN_DIM + quad8;
    const unsigned short* hp = hin + (size_t)arow * HID + quad8;

    f32x4 acc0 = {0.f, 0.f, 0.f, 0.f};   // gate cols 0..15  (i, f)
    f32x4 acc1 = {0.f, 0.f, 0.f, 0.f};   // gate cols 16..31 (g, o)

    // ---- x part of K (k 0..255, f32 -> bf16 in-register)
    #pragma unroll
    for (int kt = 0; kt < 4; ++kt) {
      #pragma unroll
      for (int s = 0; s < 2; ++s) {
        const int k = kt * 64 + s * 32;
        float4 f0 = *reinterpret_cast<const float4*>(xp + k);
        float4 f1 = *reinterpret_cast<const float4*>(xp + k + 4);
        u16x8 u = {f2bf(f0.x), f2bf(f0.y), f2bf(f0.z), f2bf(f0.w),
                   f2bf(f1.x), f2bf(f1.y), f2bf(f1.z), f2bf(f1.w)};
        bf16x8 a  = __builtin_bit_cast(bf16x8, u);
        bf16x8 b0 = *reinterpret_cast<const bf16x8*>(Bp0 + k);
        bf16x8 b1 = *reinterpret_cast<const bf16x8*>(Bp1 + k);
        acc0 = __builtin_amdgcn_mfma_f32_16x16x32_bf16(a, b0, acc0, 0, 0, 0);
        acc1 = __builtin_amdgcn_mfma_f32_16x16x32_bf16(a, b1, acc1, 0, 0, 0);
      }
    }
    // ---- h part of K (k 256..1279, bf16 direct from global)
    #pragma unroll
    for (int kt = 4; kt < 20; ++kt) {
      #pragma unroll
      for (int s = 0; s < 2; ++s) {
        const int k = kt * 64 + s * 32;
        bf16x8 a  = *reinterpret_cast<const bf16x8*>(hp + (k - IN_DIM));
        bf16x8 b0 = *reinterpret_cast<const bf16x8*>(Bp0 + k);
        bf16x8 b1 = *reinterpret_cast<const bf16x8*>(Bp1 + k);
        acc0 = __builtin_amdgcn_mfma_f32_16x16x32_bf16(a, b0, acc0, 0, 0, 0);
        acc1 = __builtin_amdgcn_mfma_f32_16x16x32_bf16(a, b1, acc1, 0, 0, 0);
      }
    }

    // ---- spill gates to LDS (C/D layout: row = quad*4+r, col = lane&15)
    #pragma unroll
    for (int r = 0; r < 4; ++r) {
      Gs[wave * 16 + quad * 4 + r][col]      = acc0[r];
      Gs[wave * 16 + quad * 4 + r][16 + col] = acc1[r];
    }
    __syncthreads();

    // ---- cell update for this thread's two (row, j) cells
    float* out_t = out + (size_t)t * BATCH * HID;
    {
      float ig = Gs[er][jj]      + bi;
      float fg = Gs[er][8 + jj]  + bf_;
      float gg = Gs[er][16 + jj] + bg;
      float og = Gs[er][24 + jj] + bo;
      ig = 1.f / (1.f + __expf(-ig));
      fg = 1.f / (1.f + __expf(-fg));
      og = 1.f / (1.f + __expf(-og));
      gg = tanhf(gg);
      cA = fg * cA + ig * gg;
      hA = og * tanhf(cA);
      out_t[offA] = hA;
      hout[offA]  = f2bf(hA);
    }
    {
      float ig = Gs[er + 32][jj]      + bi;
      float fg = Gs[er + 32][8 + jj]  + bf_;
      float gg = Gs[er + 32][16 + jj] + bg;
      float og = Gs[er + 32][24 + jj] + bo;
      ig = 1.f / (1.f + __expf(-ig));
      fg = 1.f / (1.f + __expf(-fg));
      og = 1.f / (1.f + __expf(-og));
      gg = tanhf(gg);
      cB = fg * cB + ig * gg;
      hB = og * tanhf(cB);
      out_t[offB] = hB;
      hout[offB]  = f2bf(hB);
    }

    // next step reads hout everywhere; ping-pong means one sync/step suffices
    grid.sync();
  }

  // ---- finals: out[T] = h_final, out[T]+B*H = c_final
  const size_t fin = (size_t)T_STEPS * BATCH * HID;
  out[fin + offA] = hA;
  out[fin + BATCH * HID + offA] = cA;
  out[fin + offB] = hB;
  out[fin + BATCH * HID + offB] = cB;
}

extern "C" void kernel_launch(void* const* d_in, const int* in_sizes, int n_in,
                              void* d_out, int out_size, void* d_ws, size_t ws_size,
                              hipStream_t stream) {
  const float* x   = (const float*)d_in[0];
  const float* h0  = (const float*)d_in[1];
  const float* c0  = (const float*)d_in[2];
  const float* Wih = (const float*)d_in[3];
  const float* Whh = (const float*)d_in[4];
  const float* bih = (const float*)d_in[5];
  const float* bhh = (const float*)d_in[6];
  float* out = (float*)d_out;

  char* ws = (char*)d_ws;
  unsigned short* Wbf  = (unsigned short*)ws;                       // 10,485,760 B
  float*          bsum = (float*)(ws + 10485760);                   //     16,384 B
  unsigned short* hbf  = (unsigned short*)(ws + 10485760 + 16384);  //  2x524,288 B

  cast_weights<<<dim3((GATES * (KDIM / 4) + 255) / 256), 256, 0, stream>>>(Wih, Whh, Wbf);
  init_state<<<dim3((BATCH * HID + 255) / 256), 256, 0, stream>>>(h0, bih, bhh, hbf, bsum);

  void* args[] = {(void*)&x, (void*)&Wbf, (void*)&bsum, (void*)&c0,
                  (void*)&hbf, (void*)&out};
  hipLaunchCooperativeKernel(lstm_persistent, dim3(256), dim3(256), args, 0, stream);
}

// Round 2
// 10791.839 us; speedup vs baseline: 1.9439x; 1.9439x over previous
//
#include <hip/hip_runtime.h>

// LSTM: T=512, B=128, I=256, H=1024.
// Persistent kernel (cooperative launch for co-residency guarantee), all 512
// timesteps inside. Replaces cg::grid.sync() (~40us/step, system-scope) with a
// hand-rolled agent-scope barrier (~2-4us/step), split into TWO independent
// 128-block barriers (row-group rg=0/1 recurrences never interact).
//  - W bf16 slice resident in LDS for the whole kernel (82 KB/block).
//  - A (x|h) MFMA fragments loaded directly from global.
//  - c state in 2 registers/thread; h ping-pongs in ws as bf16.
//  - x-part MFMAs (independent of h_{t-1}) run BEFORE the barrier wait.
// Tiling: 2 row-groups x 128 col-groups, 64 rows x 32 gate-cols per block,
// 16x16x32 bf16 MFMA.

#define T_STEPS 512
#define BATCH   128
#define IN_DIM  256
#define HID     1024
#define GATES   4096   // 4*HID
#define KDIM    1280   // IN_DIM + HID

typedef __bf16          bf16x8 __attribute__((ext_vector_type(8)));
typedef unsigned short  u16x8  __attribute__((ext_vector_type(8)));
typedef float           f32x4  __attribute__((ext_vector_type(4)));

__device__ __forceinline__ unsigned short f2bf(float f) {
  unsigned int u = __builtin_bit_cast(unsigned int, f);
  unsigned int r = (u + 0x7FFFu + ((u >> 16) & 1u)) >> 16;  // RNE
  return (unsigned short)r;
}

// W_ih [4096x256] + W_hh [4096x1024] f32 -> fused W_bf [4096][1280] bf16
__global__ void cast_weights(const float* __restrict__ Wih,
                             const float* __restrict__ Whh,
                             unsigned short* __restrict__ Wbf) {
  int gid = blockIdx.x * blockDim.x + threadIdx.x;
  if (gid >= GATES * (KDIM / 4)) return;
  int n  = gid / (KDIM / 4);
  int k4 = (gid % (KDIM / 4)) * 4;
  float4 v;
  if (k4 < IN_DIM) v = *reinterpret_cast<const float4*>(Wih + (size_t)n * IN_DIM + k4);
  else             v = *reinterpret_cast<const float4*>(Whh + (size_t)n * HID + (k4 - IN_DIM));
  ushort4 o;
  o.x = f2bf(v.x); o.y = f2bf(v.y); o.z = f2bf(v.z); o.w = f2bf(v.w);
  *reinterpret_cast<ushort4*>(Wbf + (size_t)n * KDIM + k4) = o;
}

__global__ void init_state(const float* __restrict__ h0,
                           const float* __restrict__ bih,
                           const float* __restrict__ bhh,
                           unsigned short* __restrict__ hbf0,
                           float* __restrict__ bsum,
                           int* __restrict__ bar) {
  int i = blockIdx.x * blockDim.x + threadIdx.x;
  if (i < BATCH * HID) hbf0[i] = f2bf(h0[i]);
  if (i < GATES) bsum[i] = bih[i] + bhh[i];
  if (i < 1024) bar[i] = 0;   // barrier state: monotone counters, start at 0
}

// ---- agent-scope split barrier -------------------------------------------
// Per row-group (128 blocks): 8 sub-counters (16 blocks each) -> 1 main
// counter -> generation flag. Monotone counts (no reset -> no ABA).
__device__ __forceinline__ void rg_arrive(int* sub, int* cnt, int* gen,
                                          int t, int grp) {
  // block's h stores are in L2 (each wave drained vmcnt before s_barrier);
  // release fence writes XCD L2 back so other XCDs can see them.
  __builtin_amdgcn_fence(__ATOMIC_RELEASE, "agent");
  int v = __hip_atomic_fetch_add(&sub[grp * 32], 1, __ATOMIC_ACQ_REL,
                                 __HIP_MEMORY_SCOPE_AGENT);
  if (v == 16 * (t + 1) - 1) {
    int w = __hip_atomic_fetch_add(cnt, 1, __ATOMIC_ACQ_REL,
                                   __HIP_MEMORY_SCOPE_AGENT);
    if (w == 8 * (t + 1) - 1)
      __hip_atomic_store(gen, t + 1, __ATOMIC_RELEASE,
                         __HIP_MEMORY_SCOPE_AGENT);
  }
}

__device__ __forceinline__ void rg_wait(int* gen, int t) {
  while (__hip_atomic_load(gen, __ATOMIC_RELAXED, __HIP_MEMORY_SCOPE_AGENT) < t)
    __builtin_amdgcn_s_sleep(1);
  // invalidate this CU's L1 + XCD L2 so h reads see remote writes
  __builtin_amdgcn_fence(__ATOMIC_ACQUIRE, "agent");
}

__global__ __launch_bounds__(256) void lstm_persistent(
    const float* __restrict__ x,              // [T][B][I] f32
    const unsigned short* __restrict__ Wbf,   // [GATES][KDIM] bf16
    const float* __restrict__ bsum,           // [GATES]
    const float* __restrict__ c0,             // [B][H] f32
    unsigned short* __restrict__ hbf,         // 2 x [B][H] bf16 ping-pong
    int* __restrict__ bar,                    // barrier state (1024 ints)
    float* __restrict__ out)                  // [T][B][H] + h_final + c_final
{
  // Bs row stride 1288 shorts = 644 words; 644 % 32 = 4. Resident all steps.
  __shared__ __align__(16) unsigned short Bs[32][1288];   // 82,432 B
  __shared__ __align__(16) float Gs[64][36];              //  9,216 B

  const int tid  = threadIdx.x;
  const int bid  = blockIdx.x;
  const int cg_  = bid & 127;           // column group: 8 hidden j's
  const int rg   = bid >> 7;            // row group: 64 batch rows
  const int row0 = rg * 64;
  const int j0   = cg_ * 8;

  const int wave  = tid >> 6;
  const int lane  = tid & 63;
  const int col   = lane & 15;
  const int quad  = lane >> 4;
  const int quad8 = quad * 8;
  const int mrow  = wave * 16 + col;    // this lane's A row within tile
  const int arow  = row0 + mrow;        // global batch row for A fragments

  // barrier pointers for this row-group
  int* rb  = bar + rg * 512;            // 2 KB apart
  int* cnt = rb;
  int* gen = rb + 32;
  int* sub = rb + 64;                   // 8 counters, 128 B apart
  const int grp = cg_ & 7;

  // ---- load resident B tile: [32 gate-cols][1280 k]
  {
    const int wrow = tid >> 3;          // 0..31 tile gate-col
    const int kcB  = tid & 7;           // 0..7  16B chunk within 64k
    const int gB = wrow >> 3, jjB = wrow & 7;
    const unsigned short* wsrc =
        Wbf + (size_t)(gB * HID + j0 + jjB) * KDIM + kcB * 8;
    #pragma unroll
    for (int kt = 0; kt < KDIM / 64; ++kt)
      *reinterpret_cast<uint4*>(&Bs[wrow][kt * 64 + kcB * 8]) =
          *reinterpret_cast<const uint4*>(wsrc + kt * 64);
  }

  // ---- epilogue ownership (step-invariant)
  const int er = tid >> 3;              // 0..31
  const int jj = tid & 7;
  const int j  = j0 + jj;
  const size_t offA = (size_t)(row0 + er) * HID + j;
  const size_t offB = (size_t)(row0 + er + 32) * HID + j;
  float cA = c0[offA], cB = c0[offB];
  float hA = 0.f, hB = 0.f;
  const float bi  = bsum[j];
  const float bf_ = bsum[HID + j];
  const float bg  = bsum[2 * HID + j];
  const float bo  = bsum[3 * HID + j];

  const unsigned short* Bp0 = &Bs[col][quad8];
  const unsigned short* Bp1 = &Bs[16 + col][quad8];

  __syncthreads();

  for (int t = 0; t < T_STEPS; ++t) {
    const unsigned short* hin  = hbf + (size_t)(t & 1) * BATCH * HID;
    unsigned short*       hout = hbf + (size_t)((t + 1) & 1) * BATCH * HID;
    const float* xp = x + ((size_t)t * BATCH + arow) * IN_DIM + quad8;
    const unsigned short* hp = hin + (size_t)arow * HID + quad8;

    f32x4 acc0 = {0.f, 0.f, 0.f, 0.f};   // gate cols 0..15  (i, f)
    f32x4 acc1 = {0.f, 0.f, 0.f, 0.f};   // gate cols 16..31 (g, o)

    // ---- x part of K (k 0..255): independent of h_{t-1}, runs BEFORE the
    //      barrier wait to hide other blocks' arrival jitter.
    #pragma unroll
    for (int kt = 0; kt < 4; ++kt) {
      #pragma unroll
      for (int s = 0; s < 2; ++s) {
        const int k = kt * 64 + s * 32;
        float4 f0 = *reinterpret_cast<const float4*>(xp + k);
        float4 f1 = *reinterpret_cast<const float4*>(xp + k + 4);
        u16x8 u = {f2bf(f0.x), f2bf(f0.y), f2bf(f0.z), f2bf(f0.w),
                   f2bf(f1.x), f2bf(f1.y), f2bf(f1.z), f2bf(f1.w)};
        bf16x8 a  = __builtin_bit_cast(bf16x8, u);
        bf16x8 b0 = *reinterpret_cast<const bf16x8*>(Bp0 + k);
        bf16x8 b1 = *reinterpret_cast<const bf16x8*>(Bp1 + k);
        acc0 = __builtin_amdgcn_mfma_f32_16x16x32_bf16(a, b0, acc0, 0, 0, 0);
        acc1 = __builtin_amdgcn_mfma_f32_16x16x32_bf16(a, b1, acc1, 0, 0, 0);
      }
    }

    // ---- wait until h_{t-1} is published (gen >= t); t=0 passes through
    if (tid == 0) rg_wait(gen, t);
    __syncthreads();

    // ---- h part of K (k 256..1279, bf16 direct from global)
    #pragma unroll
    for (int kt = 4; kt < 20; ++kt) {
      #pragma unroll
      for (int s = 0; s < 2; ++s) {
        const int k = kt * 64 + s * 32;
        bf16x8 a  = *reinterpret_cast<const bf16x8*>(hp + (k - IN_DIM));
        bf16x8 b0 = *reinterpret_cast<const bf16x8*>(Bp0 + k);
        bf16x8 b1 = *reinterpret_cast<const bf16x8*>(Bp1 + k);
        acc0 = __builtin_amdgcn_mfma_f32_16x16x32_bf16(a, b0, acc0, 0, 0, 0);
        acc1 = __builtin_amdgcn_mfma_f32_16x16x32_bf16(a, b1, acc1, 0, 0, 0);
      }
    }

    // ---- spill gates to LDS (C/D layout: row = quad*4+r, col = lane&15)
    #pragma unroll
    for (int r = 0; r < 4; ++r) {
      Gs[wave * 16 + quad * 4 + r][col]      = acc0[r];
      Gs[wave * 16 + quad * 4 + r][16 + col] = acc1[r];
    }
    __syncthreads();

    // ---- cell update for this thread's two (row, j) cells
    float* out_t = out + (size_t)t * BATCH * HID;
    {
      float ig = Gs[er][jj]      + bi;
      float fg = Gs[er][8 + jj]  + bf_;
      float gg = Gs[er][16 + jj] + bg;
      float og = Gs[er][24 + jj] + bo;
      ig = 1.f / (1.f + __expf(-ig));
      fg = 1.f / (1.f + __expf(-fg));
      og = 1.f / (1.f + __expf(-og));
      gg = tanhf(gg);
      cA = fg * cA + ig * gg;
      hA = og * tanhf(cA);
      __builtin_nontemporal_store(hA, &out_t[offA]);  // never re-read: keep L2 clean
      hout[offA] = f2bf(hA);
    }
    {
      float ig = Gs[er + 32][jj]      + bi;
      float fg = Gs[er + 32][8 + jj]  + bf_;
      float gg = Gs[er + 32][16 + jj] + bg;
      float og = Gs[er + 32][24 + jj] + bo;
      ig = 1.f / (1.f + __expf(-ig));
      fg = 1.f / (1.f + __expf(-fg));
      og = 1.f / (1.f + __expf(-og));
      gg = tanhf(gg);
      cB = fg * cB + ig * gg;
      hB = og * tanhf(cB);
      __builtin_nontemporal_store(hB, &out_t[offB]);
      hout[offB] = f2bf(hB);
    }

    // drain this wave's stores, rendezvous block, then publish h_t
    asm volatile("s_waitcnt vmcnt(0)" ::: "memory");
    __syncthreads();
    if (tid == 0) rg_arrive(sub, cnt, gen, t, grp);
  }

  // ---- finals: out[T] = h_final, out[T]+B*H = c_final
  const size_t fin = (size_t)T_STEPS * BATCH * HID;
  __builtin_nontemporal_store(hA, &out[fin + offA]);
  __builtin_nontemporal_store(cA, &out[fin + BATCH * HID + offA]);
  __builtin_nontemporal_store(hB, &out[fin + offB]);
  __builtin_nontemporal_store(cB, &out[fin + BATCH * HID + offB]);
}

extern "C" void kernel_launch(void* const* d_in, const int* in_sizes, int n_in,
                              void* d_out, int out_size, void* d_ws, size_t ws_size,
                              hipStream_t stream) {
  const float* x   = (const float*)d_in[0];
  const float* h0  = (const float*)d_in[1];
  const float* c0  = (const float*)d_in[2];
  const float* Wih = (const float*)d_in[3];
  const float* Whh = (const float*)d_in[4];
  const float* bih = (const float*)d_in[5];
  const float* bhh = (const float*)d_in[6];
  float* out = (float*)d_out;

  char* ws = (char*)d_ws;
  unsigned short* Wbf  = (unsigned short*)ws;                       // 10,485,760 B
  float*          bsum = (float*)(ws + 10485760);                   //     16,384 B
  unsigned short* hbf  = (unsigned short*)(ws + 10485760 + 16384);  //  2x524,288 B
  int*            bar  = (int*)(ws + 10485760 + 16384 + 1048576);   //      4,096 B

  cast_weights<<<dim3((GATES * (KDIM / 4) + 255) / 256), 256, 0, stream>>>(Wih, Whh, Wbf);
  init_state<<<dim3((BATCH * HID + 255) / 256), 256, 0, stream>>>(h0, bih, bhh, hbf,
                                                                  bsum, bar);

  void* args[] = {(void*)&x, (void*)&Wbf, (void*)&bsum, (void*)&c0,
                  (void*)&hbf, (void*)&bar, (void*)&out};
  hipLaunchCooperativeKernel(lstm_persistent, dim3(256), dim3(256), args, 0, stream);
}